// Round 5
// baseline (756.595 us; speedup 1.0000x reference)
//
#include <hip/hip_runtime.h>
#include <stdint.h>
#include <type_traits>

// ---------------------------------------------------------------------------
// Problem constants: B=32, S=256, HID=1024, HEADS=16, DK=64, CLUE(runtime)=64
// ---------------------------------------------------------------------------
typedef __bf16 bf16_t;
typedef bf16_t bf16x8 __attribute__((ext_vector_type(8)));
typedef float f32x4 __attribute__((ext_vector_type(4)));

__device__ __forceinline__ unsigned short f2bf(float f) {
  union { float f; uint32_t u; } v; v.f = f;
  uint32_t u = v.u;
  uint32_t r = (u + 0x7FFFu + ((u >> 16) & 1u)) >> 16;  // round-to-nearest-even
  return (unsigned short)r;
}

// ---------------------------------------------------------------------------
// bias[i][j] = emb[fp[i][j]]; fp: |i-j| in the two diagonal blocks, else 1
// ---------------------------------------------------------------------------
__global__ void bias_kernel(const float* __restrict__ emb,
                            const int* __restrict__ cluep,
                            float* __restrict__ bias) {
  int i = blockIdx.x, j = threadIdx.x;
  int clue = cluep[0];
  int d;
  if (i >= clue && j >= clue) d = abs(i - j);
  else if (i < clue && j < clue) d = abs(i - j);
  else d = 1;
  bias[i * 256 + j] = emb[d];
}

// embedding output = bias broadcast to [B,H,S,S]  (33.5M floats)
__global__ void emb_bcast(const float* __restrict__ bias, float* __restrict__ out) {
  const float4* b4 = reinterpret_cast<const float4*>(bias);
  float4* o4 = reinterpret_cast<float4*>(out);
  const int n4 = 33554432 / 4;
  for (int i = blockIdx.x * blockDim.x + threadIdx.x; i < n4; i += gridDim.x * blockDim.x)
    o4[i] = b4[i & 16383];
}

// W [K=1024][N=1024] f32  ->  WT [N][K] bf16   (32x32 LDS tile transpose)
__global__ __launch_bounds__(256) void wtrans(const float* __restrict__ in,
                                              unsigned short* __restrict__ out) {
  __shared__ float tile[32][33];
  const int t = threadIdx.x;
  const int tx = t & 31, ty = t >> 5;           // ty in [0,8)
  const int k0 = blockIdx.x * 32, n0 = blockIdx.y * 32;
  #pragma unroll
  for (int p = 0; p < 4; ++p) {
    int r = ty + p * 8;
    tile[r][tx] = in[(size_t)(k0 + r) * 1024 + n0 + tx];
  }
  __syncthreads();
  #pragma unroll
  for (int p = 0; p < 4; ++p) {
    int r = ty + p * 8;
    out[(size_t)(n0 + r) * 1024 + k0 + tx] = f2bf(tile[tx][r]);
  }
}

// ---------------------------------------------------------------------------
// GEMM: C[M=8192][1024] = A[M][1024] @ BT^T + bvec.  128x128 tile, BK=64,
// 4 waves (2x2 of 64x64), mfma_f32_16x16x32_bf16.
// AMODE 0: A f32 (convert during staging)   1: A bf16
// OMODE 0: C bf16 [M][1024]   1: C bf16 transposed per head -> vhT[b,h,d,s]
//       2: C f32 [M][1024]
// ---------------------------------------------------------------------------
constexpr int GK = 1024, GN = 1024;
constexpr int BM = 128, BK = 64, LDT = BK + 8;   // +8 bf16 pad = 16B, keeps rows 16B-aligned

template<int AMODE, int OMODE>
__global__ __launch_bounds__(256, 2) void gemm_kernel(
    const void* __restrict__ Av, const unsigned short* __restrict__ BT,
    const float* __restrict__ bvec, void* __restrict__ Cout) {
  __shared__ unsigned short Alds[BM * LDT];
  __shared__ unsigned short Blds[BM * LDT];
  const int t = threadIdx.x;
  const int lane = t & 63;
  const int w = t >> 6;
  const int wr = (w >> 1) * 64;
  const int wc = (w & 1) * 64;
  const int m0 = blockIdx.y * BM;
  const int n0 = blockIdx.x * BM;
  const int lg = lane >> 4;      // k-group
  const int lr = lane & 15;      // row/col within 16-tile

  f32x4 acc[4][4] = {};

  for (int k0 = 0; k0 < GK; k0 += BK) {
    if constexpr (AMODE == 0) {
      const float* A = (const float*)Av;
      #pragma unroll
      for (int i = 0; i < 8; ++i) {
        int flat = i * 256 + t;
        int row = flat >> 4, kq = flat & 15;
        float4 va = *reinterpret_cast<const float4*>(A + (size_t)(m0 + row) * GK + k0 + kq * 4);
        ushort4 pk;
        pk.x = f2bf(va.x); pk.y = f2bf(va.y); pk.z = f2bf(va.z); pk.w = f2bf(va.w);
        *reinterpret_cast<ushort4*>(&Alds[row * LDT + kq * 4]) = pk;
      }
    } else {
      const unsigned short* A = (const unsigned short*)Av;
      #pragma unroll
      for (int i = 0; i < 4; ++i) {
        int flat = i * 256 + t;
        int row = flat >> 3, ck = flat & 7;
        uint4 vv = *reinterpret_cast<const uint4*>(A + (size_t)(m0 + row) * GK + k0 + ck * 8);
        *reinterpret_cast<uint4*>(&Alds[row * LDT + ck * 8]) = vv;
      }
    }
    #pragma unroll
    for (int i = 0; i < 4; ++i) {
      int flat = i * 256 + t;
      int row = flat >> 3, ck = flat & 7;
      uint4 vv = *reinterpret_cast<const uint4*>(BT + (size_t)(n0 + row) * GK + k0 + ck * 8);
      *reinterpret_cast<uint4*>(&Blds[row * LDT + ck * 8]) = vv;
    }
    __syncthreads();
    #pragma unroll
    for (int ks = 0; ks < 2; ++ks) {
      bf16x8 af[4], bfr[4];
      #pragma unroll
      for (int m = 0; m < 4; ++m)
        af[m] = *reinterpret_cast<const bf16x8*>(&Alds[(wr + m * 16 + lr) * LDT + ks * 32 + lg * 8]);
      #pragma unroll
      for (int n = 0; n < 4; ++n)
        bfr[n] = *reinterpret_cast<const bf16x8*>(&Blds[(wc + n * 16 + lr) * LDT + ks * 32 + lg * 8]);
      #pragma unroll
      for (int m = 0; m < 4; ++m) {
        #pragma unroll
        for (int n = 0; n < 4; ++n)
          acc[m][n] = __builtin_amdgcn_mfma_f32_16x16x32_bf16(af[m], bfr[n], acc[m][n], 0, 0, 0);
      }
    }
    __syncthreads();
  }

  // epilogue: C/D layout col = lane&15, row = (lane>>4)*4 + j   [m89/m91-verified]
  #pragma unroll
  for (int m = 0; m < 4; ++m) {
    #pragma unroll
    for (int n = 0; n < 4; ++n) {
      const int col = n0 + wc + n * 16 + lr;
      const float bv = bvec[col];
      const int rbase = m0 + wr + m * 16 + lg * 4;
      if constexpr (OMODE == 0) {
        unsigned short* C = (unsigned short*)Cout;
        #pragma unroll
        for (int j = 0; j < 4; ++j)
          C[(size_t)(rbase + j) * GN + col] = f2bf(acc[m][n][j] + bv);
      } else if constexpr (OMODE == 1) {
        unsigned short* C = (unsigned short*)Cout;     // vhT[((b*16+h)*64+d)*256 + s]
        const int b = rbase >> 8, s = rbase & 255;
        const int h = col >> 6, d = col & 63;
        ushort4 pk;
        pk.x = f2bf(acc[m][n][0] + bv);
        pk.y = f2bf(acc[m][n][1] + bv);
        pk.z = f2bf(acc[m][n][2] + bv);
        pk.w = f2bf(acc[m][n][3] + bv);
        *reinterpret_cast<ushort4*>(&C[(size_t)((b * 16 + h) * 64 + d) * 256 + s]) = pk;
      } else {
        float* C = (float*)Cout;
        #pragma unroll
        for (int j = 0; j < 4; ++j)
          C[(size_t)(rbase + j) * GN + col] = acc[m][n][j] + bv;
      }
    }
  }
}

// ---------------------------------------------------------------------------
// Attention: one block per (b, h, half-of-128-rows). 4 waves x 32 q-rows,
// waves fully independent (no __syncthreads needed).
// Phase 1: S = Q K^T * scale + bias, p = keep?exp(s):0 -> P (LDS bf16,
//          XOR-swizzled [128][256], exactly 64KB) + in-register rowsums.
// Phase 2: att = P * (keep_row ? 1/sum : 0)  (f32, coalesced float4)
// Phase 3: O = P @ V (vhT), scaled by inv -> attn_out bf16
// No max-subtraction needed: |scores| <= ~6 (weights are 0.02-scaled), so
// exp(s)/sum(exp(s)) == softmax exactly; fully-masked rows -> sum=0 -> inv=0,
// matching reference's softmax*keep (exp(-1e9-max) underflows to 0 there).
// ---------------------------------------------------------------------------
__device__ __forceinline__ int pidx(int row, int c) {
  // ushort-unit index with XOR swizzle on bits 3..5 (16B chunk within 128B):
  // phase-3 column reads hit 8 distinct chunks across rows -> structural-min.
  return (row * 256 + c) ^ ((row & 7) << 3);
}

__global__ __launch_bounds__(256, 2) void attn_kernel(
    const unsigned short* __restrict__ qh, const unsigned short* __restrict__ kh,
    const unsigned short* __restrict__ vhT, const float* __restrict__ bias,
    const int* __restrict__ mask, float* __restrict__ att_out,
    unsigned short* __restrict__ attn_out) {
  __shared__ unsigned short P[128 * 256];   // 64 KB exactly
  const int t = threadIdx.x;
  const int lane = t & 63, w = t >> 6;
  const int half = blockIdx.x, h = blockIdx.y, b = blockIdx.z;
  const int rows0 = half * 128;          // first q-row of block (absolute in S)
  const int wrow = w * 32;               // wave's first row (block-local)
  const int lg = lane >> 4, lr = lane & 15;
  const float scale = 0.125f;            // DK^-0.5

  // Q fragments (rows stay in registers for the whole kernel)
  bf16x8 qf[2][2];
  #pragma unroll
  for (int m = 0; m < 2; ++m)
    #pragma unroll
    for (int ks = 0; ks < 2; ++ks)
      qf[m][ks] = *reinterpret_cast<const bf16x8*>(
          qh + (size_t)(b * 256 + rows0 + wrow + m * 16 + lr) * 1024 + h * 64 + ks * 32 + lg * 8);

  int rowm[2][4];
  #pragma unroll
  for (int m = 0; m < 2; ++m)
    #pragma unroll
    for (int j = 0; j < 4; ++j)
      rowm[m][j] = mask[b * 256 + rows0 + wrow + m * 16 + lg * 4 + j];

  float psum[2][4] = {};

  for (int ct = 0; ct < 4; ++ct) {       // 64-column chunks
    f32x4 acc[2][4] = {};
    #pragma unroll
    for (int ks = 0; ks < 2; ++ks) {
      bf16x8 kf[4];
      #pragma unroll
      for (int n = 0; n < 4; ++n)
        kf[n] = *reinterpret_cast<const bf16x8*>(
            kh + (size_t)(b * 256 + ct * 64 + n * 16 + lr) * 1024 + h * 64 + ks * 32 + lg * 8);
      #pragma unroll
      for (int m = 0; m < 2; ++m)
        #pragma unroll
        for (int n = 0; n < 4; ++n)
          acc[m][n] = __builtin_amdgcn_mfma_f32_16x16x32_bf16(qf[m][ks], kf[n], acc[m][n], 0, 0, 0);
    }
    #pragma unroll
    for (int n = 0; n < 4; ++n) {
      const int c = ct * 64 + n * 16 + lr;
      const int colm = mask[b * 256 + c];
      #pragma unroll
      for (int m = 0; m < 2; ++m) {
        const int rloc = wrow + m * 16 + lg * 4;
        #pragma unroll
        for (int j = 0; j < 4; ++j) {
          float s = acc[m][n][j] * scale + bias[(rows0 + rloc + j) * 256 + c];
          float p = (rowm[m][j] & colm) ? __expf(s) : 0.f;
          psum[m][j] += p;
          P[pidx(rloc + j, c)] = f2bf(p);
        }
      }
    }
  }

  // row-sum: butterfly over the 16 column-lanes of each lg-group.
  // After this, every lane holds the sums for its 8 rows (m,j).
  #pragma unroll
  for (int off = 1; off < 16; off <<= 1)
    #pragma unroll
    for (int m = 0; m < 2; ++m)
      #pragma unroll
      for (int j = 0; j < 4; ++j)
        psum[m][j] += __shfl_xor(psum[m][j], off);

  // Phase 2: att output (normalized; masked rows give inv=0).
  // Row sums fetched via shuffle from the owning lg-group (compile-time idx).
  const size_t att_base = (size_t)(b * 16 + h) * 65536;
  #pragma unroll
  for (int it = 0; it < 16; ++it) {
    const int m2 = it >> 3;
    const int lg2 = (it >> 1) & 3;
    const int b0 = (2 * it) & 3;
    const float s0 = __shfl(psum[m2][b0], lg2 * 16);
    const float s1 = __shfl(psum[m2][b0 + 1], lg2 * 16);
    const int rloc = wrow + it * 2 + (lane >> 5);
    const int rabs = rows0 + rloc;
    const float sum = (lane >= 32) ? s1 : s0;
    const float inv = sum > 0.f ? 1.f / sum : 0.f;
    const int c8 = (lane & 31) * 8;
    bf16x8 pv = *reinterpret_cast<const bf16x8*>(&P[(rloc * 256 + c8) ^ ((rloc & 7) << 3)]);
    float4 o1, o2;
    o1.x = (float)pv[0] * inv; o1.y = (float)pv[1] * inv;
    o1.z = (float)pv[2] * inv; o1.w = (float)pv[3] * inv;
    o2.x = (float)pv[4] * inv; o2.y = (float)pv[5] * inv;
    o2.z = (float)pv[6] * inv; o2.w = (float)pv[7] * inv;
    *reinterpret_cast<float4*>(&att_out[att_base + (size_t)rabs * 256 + c8]) = o1;
    *reinterpret_cast<float4*>(&att_out[att_base + (size_t)rabs * 256 + c8 + 4]) = o2;
  }

  // Phase 3: O = P @ V
  f32x4 oacc[2][4] = {};
  for (int ks = 0; ks < 8; ++ks) {
    bf16x8 pa[2], vf[4];
    #pragma unroll
    for (int m = 0; m < 2; ++m)
      pa[m] = *reinterpret_cast<const bf16x8*>(&P[pidx(wrow + m * 16 + lr, ks * 32 + lg * 8)]);
    #pragma unroll
    for (int dn = 0; dn < 4; ++dn)
      vf[dn] = *reinterpret_cast<const bf16x8*>(
          vhT + (size_t)((b * 16 + h) * 64 + dn * 16 + lr) * 256 + ks * 32 + lg * 8);
    #pragma unroll
    for (int m = 0; m < 2; ++m)
      #pragma unroll
      for (int dn = 0; dn < 4; ++dn)
        oacc[m][dn] = __builtin_amdgcn_mfma_f32_16x16x32_bf16(pa[m], vf[dn], oacc[m][dn], 0, 0, 0);
  }
  #pragma unroll
  for (int m = 0; m < 2; ++m) {
    #pragma unroll
    for (int dn = 0; dn < 4; ++dn) {
      #pragma unroll
      for (int j = 0; j < 4; ++j) {
        const int rloc = wrow + m * 16 + lg * 4 + j;
        const float sum = psum[m][j];      // this lane owns row rloc's sum
        const float inv = sum > 0.f ? 1.f / sum : 0.f;
        attn_out[(size_t)(b * 256 + rows0 + rloc) * 1024 + h * 64 + dn * 16 + lr] =
            f2bf(oacc[m][dn][j] * inv);
      }
    }
  }
}

// ---------------------------------------------------------------------------
extern "C" void kernel_launch(void* const* d_in, const int* in_sizes, int n_in,
                              void* d_out, int out_size, void* d_ws, size_t ws_size,
                              hipStream_t stream) {
  (void)in_sizes; (void)n_in; (void)out_size; (void)ws_size;
  const float* q    = (const float*)d_in[0];
  const float* k    = (const float*)d_in[1];
  const float* v    = (const float*)d_in[2];
  const int*   clue = (const int*)d_in[3];
  const int*   mask = (const int*)d_in[4];
  const float* Wq   = (const float*)d_in[5];
  const float* bq   = (const float*)d_in[6];
  const float* Wk   = (const float*)d_in[7];
  const float* bk   = (const float*)d_in[8];
  const float* Wv   = (const float*)d_in[9];
  const float* bv   = (const float*)d_in[10];
  const float* Wo   = (const float*)d_in[11];
  const float* bo   = (const float*)d_in[12];
  const float* emb  = (const float*)d_in[13];

  char* ws = (char*)d_ws;
  float*          biasb = (float*)(ws);                         // 256 KB
  unsigned short* WTq   = (unsigned short*)(ws + (256u << 10));
  unsigned short* WTk   = (unsigned short*)(ws + (256u << 10) + (1u << 22));
  unsigned short* WTv   = (unsigned short*)(ws + (256u << 10) + (2u << 22));
  unsigned short* WTo   = (unsigned short*)(ws + (256u << 10) + (3u << 22));
  size_t off = (256u << 10) + (4u << 22);
  unsigned short* qh    = (unsigned short*)(ws + off); off += (16u << 20);
  unsigned short* kh    = (unsigned short*)(ws + off); off += (16u << 20);
  unsigned short* vhT   = (unsigned short*)(ws + off); off += (16u << 20);
  unsigned short* aout  = (unsigned short*)(ws + off);

  float* out  = (float*)d_out;
  float* embo = out + 8388608;     // [B,H,S,S]
  float* atto = out + 41943040;    // [B,H,S,S]

  bias_kernel<<<256, 256, 0, stream>>>(emb, clue, biasb);
  emb_bcast<<<4096, 256, 0, stream>>>(biasb, embo);
  wtrans<<<dim3(32, 32), 256, 0, stream>>>(Wq, WTq);
  wtrans<<<dim3(32, 32), 256, 0, stream>>>(Wk, WTk);
  wtrans<<<dim3(32, 32), 256, 0, stream>>>(Wv, WTv);
  wtrans<<<dim3(32, 32), 256, 0, stream>>>(Wo, WTo);

  gemm_kernel<0, 0><<<dim3(8, 64), 256, 0, stream>>>(q, WTq, bq, qh);
  gemm_kernel<0, 0><<<dim3(8, 64), 256, 0, stream>>>(k, WTk, bk, kh);
  gemm_kernel<0, 1><<<dim3(8, 64), 256, 0, stream>>>(v, WTv, bv, vhT);

  attn_kernel<<<dim3(2, 16, 32), 256, 0, stream>>>(qh, kh, vhT, biasb, mask, atto, aout);

  gemm_kernel<1, 2><<<dim3(8, 64), 256, 0, stream>>>(aout, WTo, bo, out);
}

// Round 6
// 603.569 us; speedup vs baseline: 1.2535x; 1.2535x over previous
//
#include <hip/hip_runtime.h>
#include <stdint.h>
#include <type_traits>

// ---------------------------------------------------------------------------
// Problem constants: B=32, S=256, HID=1024, HEADS=16, DK=64, CLUE(runtime)=64
// ---------------------------------------------------------------------------
typedef __bf16 bf16_t;
typedef bf16_t bf16x8 __attribute__((ext_vector_type(8)));
typedef float f32x4 __attribute__((ext_vector_type(4)));

__device__ __forceinline__ unsigned short f2bf(float f) {
  union { float f; uint32_t u; } v; v.f = f;
  uint32_t u = v.u;
  uint32_t r = (u + 0x7FFFu + ((u >> 16) & 1u)) >> 16;  // round-to-nearest-even
  return (unsigned short)r;
}

__device__ __forceinline__ void gload16(const unsigned short* g, unsigned short* l) {
  auto gp = (const __attribute__((address_space(1))) unsigned short*)(g);
  auto lp = (__attribute__((address_space(3))) unsigned short*)(l);
  __builtin_amdgcn_global_load_lds(gp, lp, 16, 0, 0);   // 16B/lane, dest = base + lane*16
}

// ---------------------------------------------------------------------------
// bias[i][j] = emb[fp[i][j]]; fp: |i-j| in the two diagonal blocks, else 1
// ---------------------------------------------------------------------------
__global__ void bias_kernel(const float* __restrict__ emb,
                            const int* __restrict__ cluep,
                            float* __restrict__ bias) {
  int i = blockIdx.x, j = threadIdx.x;
  int clue = cluep[0];
  int d;
  if (i >= clue && j >= clue) d = abs(i - j);
  else if (i < clue && j < clue) d = abs(i - j);
  else d = 1;
  bias[i * 256 + j] = emb[d];
}

// embedding output = bias broadcast to [B,H,S,S]  (33.5M floats)
__global__ void emb_bcast(const float* __restrict__ bias, float* __restrict__ out) {
  const float4* b4 = reinterpret_cast<const float4*>(bias);
  float4* o4 = reinterpret_cast<float4*>(out);
  const int n4 = 33554432 / 4;
  for (int i = blockIdx.x * blockDim.x + threadIdx.x; i < n4; i += gridDim.x * blockDim.x)
    o4[i] = b4[i & 16383];
}

// f32 -> bf16 streaming convert (8 elems/thread/iter), n = 8388608
__global__ void cvt_bf16(const float* __restrict__ in, unsigned short* __restrict__ out) {
  const int n8 = 8388608 / 8;
  for (int i = blockIdx.x * blockDim.x + threadIdx.x; i < n8; i += gridDim.x * blockDim.x) {
    float4 a = reinterpret_cast<const float4*>(in)[2 * i];
    float4 b = reinterpret_cast<const float4*>(in)[2 * i + 1];
    ushort4 p, q;
    p.x = f2bf(a.x); p.y = f2bf(a.y); p.z = f2bf(a.z); p.w = f2bf(a.w);
    q.x = f2bf(b.x); q.y = f2bf(b.y); q.z = f2bf(b.z); q.w = f2bf(b.w);
    reinterpret_cast<ushort4*>(out)[2 * i] = p;
    reinterpret_cast<ushort4*>(out)[2 * i + 1] = q;
  }
}

// W [K=1024][N=1024] f32  ->  WT [N][K] bf16   (32x32 LDS tile transpose)
__global__ __launch_bounds__(256) void wtrans(const float* __restrict__ in,
                                              unsigned short* __restrict__ out) {
  __shared__ float tile[32][33];
  const int t = threadIdx.x;
  const int tx = t & 31, ty = t >> 5;           // ty in [0,8)
  const int k0 = blockIdx.x * 32, n0 = blockIdx.y * 32;
  #pragma unroll
  for (int p = 0; p < 4; ++p) {
    int r = ty + p * 8;
    tile[r][tx] = in[(size_t)(k0 + r) * 1024 + n0 + tx];
  }
  __syncthreads();
  #pragma unroll
  for (int p = 0; p < 4; ++p) {
    int r = ty + p * 8;
    out[(size_t)(n0 + r) * 1024 + k0 + tx] = f2bf(tile[tx][r]);
  }
}

// ---------------------------------------------------------------------------
// GEMM: C[M=8192][1024] = A(bf16)[M][1024] @ BT^T + bvec.  128x128 tile, BK=64,
// 4 waves (2x2 of 64x64), mfma_f32_16x16x32_bf16.
// Staging: global_load_lds width=16, LINEAR LDS [128][64] (DMA needs linear
// dest), with pre-swizzled GLOBAL source: lane's k-chunk = (lane&7)^(row&7).
// ds_read applies the same XOR -> fragment reads spread over all 8 16B-slots
// per 128B row group = conflict-free (rule #21: both-sides-or-neither).
// OMODE 0: C bf16 [M][1024]   1: C bf16 transposed per head -> vhT[b,h,d,s]
//       2: C f32 [M][1024]
// ---------------------------------------------------------------------------
constexpr int GK = 1024, GN = 1024;

template<int OMODE>
__global__ __launch_bounds__(256, 2) void gemm_kernel(
    const unsigned short* __restrict__ A, const unsigned short* __restrict__ BT,
    const float* __restrict__ bvec, void* __restrict__ Cout) {
  __shared__ unsigned short Alds[128 * 64];   // 16 KB, linear
  __shared__ unsigned short Blds[128 * 64];   // 16 KB, linear
  const int t = threadIdx.x;
  const int lane = t & 63;
  const int w = t >> 6;
  const int wr = (w >> 1) * 64;
  const int wc = (w & 1) * 64;
  const int m0 = blockIdx.y * 128;
  const int n0 = blockIdx.x * 128;
  const int lg = lane >> 4;      // k-group
  const int lr = lane & 15;      // row/col within 16-tile

  // staging geometry: wave w stages rows [w*32, w*32+32) of both tiles.
  // instruction i covers 8 rows; lane -> row w*32+i*8+(lane>>3),
  // global 16B-chunk = (lane&7) ^ (row&7); LDS dest linear (lane*16).
  const int srow = w * 32 + (lane >> 3);            // + i*8
  const int gch  = (lane & 7) ^ ((lane >> 3) & 7);  // swizzled source chunk

  f32x4 acc[4][4] = {};

  for (int k0 = 0; k0 < GK; k0 += 64) {
    #pragma unroll
    for (int i = 0; i < 4; ++i) {
      gload16(A  + (size_t)(m0 + srow + i * 8) * GK + k0 + gch * 8,
              &Alds[(w * 32 + i * 8) * 64]);
      gload16(BT + (size_t)(n0 + srow + i * 8) * GK + k0 + gch * 8,
              &Blds[(w * 32 + i * 8) * 64]);
    }
    __syncthreads();   // compiler emits vmcnt(0) drain before barrier
    #pragma unroll
    for (int ks = 0; ks < 2; ++ks) {
      bf16x8 af[4], bfr[4];
      #pragma unroll
      for (int m = 0; m < 4; ++m) {
        const int r = wr + m * 16 + lr;                 // r&7 == lr&7
        const int cc = (ks * 4 + lg) ^ (lr & 7);        // read-side un-swizzle
        af[m] = *reinterpret_cast<const bf16x8*>(&Alds[r * 64 + cc * 8]);
      }
      #pragma unroll
      for (int n = 0; n < 4; ++n) {
        const int r = wc + n * 16 + lr;
        const int cc = (ks * 4 + lg) ^ (lr & 7);
        bfr[n] = *reinterpret_cast<const bf16x8*>(&Blds[r * 64 + cc * 8]);
      }
      #pragma unroll
      for (int m = 0; m < 4; ++m) {
        #pragma unroll
        for (int n = 0; n < 4; ++n)
          acc[m][n] = __builtin_amdgcn_mfma_f32_16x16x32_bf16(af[m], bfr[n], acc[m][n], 0, 0, 0);
      }
    }
    __syncthreads();
  }

  // epilogue: C/D layout col = lane&15, row = (lane>>4)*4 + j   [m89/m91-verified]
  #pragma unroll
  for (int m = 0; m < 4; ++m) {
    #pragma unroll
    for (int n = 0; n < 4; ++n) {
      const int col = n0 + wc + n * 16 + lr;
      const float bv = bvec[col];
      const int rbase = m0 + wr + m * 16 + lg * 4;
      if constexpr (OMODE == 0) {
        unsigned short* C = (unsigned short*)Cout;
        #pragma unroll
        for (int j = 0; j < 4; ++j)
          C[(size_t)(rbase + j) * GN + col] = f2bf(acc[m][n][j] + bv);
      } else if constexpr (OMODE == 1) {
        unsigned short* C = (unsigned short*)Cout;     // vhT[((b*16+h)*64+d)*256 + s]
        const int b = rbase >> 8, s = rbase & 255;
        const int h = col >> 6, d = col & 63;
        ushort4 pk;
        pk.x = f2bf(acc[m][n][0] + bv);
        pk.y = f2bf(acc[m][n][1] + bv);
        pk.z = f2bf(acc[m][n][2] + bv);
        pk.w = f2bf(acc[m][n][3] + bv);
        *reinterpret_cast<ushort4*>(&C[(size_t)((b * 16 + h) * 64 + d) * 256 + s]) = pk;
      } else {
        float* C = (float*)Cout;
        #pragma unroll
        for (int j = 0; j < 4; ++j)
          C[(size_t)(rbase + j) * GN + col] = acc[m][n][j] + bv;
      }
    }
  }
}

// ---------------------------------------------------------------------------
// Attention: one block per (b, h, half-of-128-rows). 4 waves x 32 q-rows,
// waves fully independent (no __syncthreads needed).
// Phase 1: S = Q K^T * scale + bias, p = keep?exp(s):0 -> P (LDS bf16,
//          XOR-swizzled [128][256], exactly 64KB) + in-register rowsums.
// Phase 2: att = P * (keep_row ? 1/sum : 0)  (f32, coalesced float4)
// Phase 3: O = P @ V (vhT), scaled by inv -> attn_out bf16
// No max-subtraction needed: |scores| <= ~6 (weights are 0.02-scaled).
// ---------------------------------------------------------------------------
__device__ __forceinline__ int pidx(int row, int c) {
  // ushort-unit index, XOR bits 3..6 with row&15: phase-1 scalar stores 2-way
  // (free), phase-2/3 b128 reads at structural minimum. Bijective per row.
  return (row * 256 + c) ^ ((row & 15) << 3);
}

__global__ __launch_bounds__(256, 2) void attn_kernel(
    const unsigned short* __restrict__ qh, const unsigned short* __restrict__ kh,
    const unsigned short* __restrict__ vhT, const float* __restrict__ bias,
    const int* __restrict__ mask, float* __restrict__ att_out,
    unsigned short* __restrict__ attn_out) {
  __shared__ unsigned short P[128 * 256];   // 64 KB exactly
  const int t = threadIdx.x;
  const int lane = t & 63, w = t >> 6;
  const int half = blockIdx.x, h = blockIdx.y, b = blockIdx.z;
  const int rows0 = half * 128;
  const int wrow = w * 32;
  const int lg = lane >> 4, lr = lane & 15;
  const float scale = 0.125f;

  bf16x8 qf[2][2];
  #pragma unroll
  for (int m = 0; m < 2; ++m)
    #pragma unroll
    for (int ks = 0; ks < 2; ++ks)
      qf[m][ks] = *reinterpret_cast<const bf16x8*>(
          qh + (size_t)(b * 256 + rows0 + wrow + m * 16 + lr) * 1024 + h * 64 + ks * 32 + lg * 8);

  int rowm[2][4];
  #pragma unroll
  for (int m = 0; m < 2; ++m)
    #pragma unroll
    for (int j = 0; j < 4; ++j)
      rowm[m][j] = mask[b * 256 + rows0 + wrow + m * 16 + lg * 4 + j];

  float psum[2][4] = {};

  for (int ct = 0; ct < 4; ++ct) {       // 64-column chunks
    f32x4 acc[2][4] = {};
    #pragma unroll
    for (int ks = 0; ks < 2; ++ks) {
      bf16x8 kf[4];
      #pragma unroll
      for (int n = 0; n < 4; ++n)
        kf[n] = *reinterpret_cast<const bf16x8*>(
            kh + (size_t)(b * 256 + ct * 64 + n * 16 + lr) * 1024 + h * 64 + ks * 32 + lg * 8);
      #pragma unroll
      for (int m = 0; m < 2; ++m)
        #pragma unroll
        for (int n = 0; n < 4; ++n)
          acc[m][n] = __builtin_amdgcn_mfma_f32_16x16x32_bf16(qf[m][ks], kf[n], acc[m][n], 0, 0, 0);
    }
    #pragma unroll
    for (int n = 0; n < 4; ++n) {
      const int c = ct * 64 + n * 16 + lr;
      const int colm = mask[b * 256 + c];
      #pragma unroll
      for (int m = 0; m < 2; ++m) {
        const int rloc = wrow + m * 16 + lg * 4;
        #pragma unroll
        for (int j = 0; j < 4; ++j) {
          float s = acc[m][n][j] * scale + bias[(rows0 + rloc + j) * 256 + c];
          float p = (rowm[m][j] & colm) ? __expf(s) : 0.f;
          psum[m][j] += p;
          P[pidx(rloc + j, c)] = f2bf(p);
        }
      }
    }
  }

  // row-sum: butterfly over the 16 column-lanes of each lg-group.
  #pragma unroll
  for (int off = 1; off < 16; off <<= 1)
    #pragma unroll
    for (int m = 0; m < 2; ++m)
      #pragma unroll
      for (int j = 0; j < 4; ++j)
        psum[m][j] += __shfl_xor(psum[m][j], off);

  // Phase 2: att output (normalized; masked rows give inv=0).
  const size_t att_base = (size_t)(b * 16 + h) * 65536;
  #pragma unroll
  for (int it = 0; it < 16; ++it) {
    const int m2 = it >> 3;
    const int lg2 = (it >> 1) & 3;
    const int b0 = (2 * it) & 3;
    const float s0 = __shfl(psum[m2][b0], lg2 * 16);
    const float s1 = __shfl(psum[m2][b0 + 1], lg2 * 16);
    const int rloc = wrow + it * 2 + (lane >> 5);
    const int rabs = rows0 + rloc;
    const float sum = (lane >= 32) ? s1 : s0;
    const float inv = sum > 0.f ? 1.f / sum : 0.f;
    const int c8 = (lane & 31) * 8;
    bf16x8 pv = *reinterpret_cast<const bf16x8*>(&P[pidx(rloc, c8)]);
    float4 o1, o2;
    o1.x = (float)pv[0] * inv; o1.y = (float)pv[1] * inv;
    o1.z = (float)pv[2] * inv; o1.w = (float)pv[3] * inv;
    o2.x = (float)pv[4] * inv; o2.y = (float)pv[5] * inv;
    o2.z = (float)pv[6] * inv; o2.w = (float)pv[7] * inv;
    *reinterpret_cast<float4*>(&att_out[att_base + (size_t)rabs * 256 + c8]) = o1;
    *reinterpret_cast<float4*>(&att_out[att_base + (size_t)rabs * 256 + c8 + 4]) = o2;
  }

  // Phase 3: O = P @ V
  f32x4 oacc[2][4] = {};
  for (int ks = 0; ks < 8; ++ks) {
    bf16x8 pa[2], vf[4];
    #pragma unroll
    for (int m = 0; m < 2; ++m)
      pa[m] = *reinterpret_cast<const bf16x8*>(&P[pidx(wrow + m * 16 + lr, ks * 32 + lg * 8)]);
    #pragma unroll
    for (int dn = 0; dn < 4; ++dn)
      vf[dn] = *reinterpret_cast<const bf16x8*>(
          vhT + (size_t)((b * 16 + h) * 64 + dn * 16 + lr) * 256 + ks * 32 + lg * 8);
    #pragma unroll
    for (int m = 0; m < 2; ++m)
      #pragma unroll
      for (int dn = 0; dn < 4; ++dn)
        oacc[m][dn] = __builtin_amdgcn_mfma_f32_16x16x32_bf16(pa[m], vf[dn], oacc[m][dn], 0, 0, 0);
  }
  #pragma unroll
  for (int m = 0; m < 2; ++m) {
    #pragma unroll
    for (int dn = 0; dn < 4; ++dn) {
      #pragma unroll
      for (int j = 0; j < 4; ++j) {
        const int rloc = wrow + m * 16 + lg * 4 + j;
        const float sum = psum[m][j];
        const float inv = sum > 0.f ? 1.f / sum : 0.f;
        attn_out[(size_t)(b * 256 + rows0 + rloc) * 1024 + h * 64 + dn * 16 + lr] =
            f2bf(oacc[m][dn][j] * inv);
      }
    }
  }
}

// ---------------------------------------------------------------------------
extern "C" void kernel_launch(void* const* d_in, const int* in_sizes, int n_in,
                              void* d_out, int out_size, void* d_ws, size_t ws_size,
                              hipStream_t stream) {
  (void)in_sizes; (void)n_in; (void)out_size; (void)ws_size;
  const float* q    = (const float*)d_in[0];
  const float* k    = (const float*)d_in[1];
  const float* v    = (const float*)d_in[2];
  const int*   clue = (const int*)d_in[3];
  const int*   mask = (const int*)d_in[4];
  const float* Wq   = (const float*)d_in[5];
  const float* bq   = (const float*)d_in[6];
  const float* Wk   = (const float*)d_in[7];
  const float* bk   = (const float*)d_in[8];
  const float* Wv   = (const float*)d_in[9];
  const float* bv   = (const float*)d_in[10];
  const float* Wo   = (const float*)d_in[11];
  const float* bo   = (const float*)d_in[12];
  const float* emb  = (const float*)d_in[13];

  char* ws = (char*)d_ws;
  float*          biasb = (float*)(ws);                         // 256 KB
  unsigned short* WTq   = (unsigned short*)(ws + (256u << 10));
  unsigned short* WTk   = (unsigned short*)(ws + (256u << 10) + (1u << 22));
  unsigned short* WTv   = (unsigned short*)(ws + (256u << 10) + (2u << 22));
  unsigned short* WTo   = (unsigned short*)(ws + (256u << 10) + (3u << 22));
  size_t off = (256u << 10) + (4u << 22);
  unsigned short* qh    = (unsigned short*)(ws + off); off += (16u << 20);
  unsigned short* kh    = (unsigned short*)(ws + off); off += (16u << 20);
  unsigned short* vhT   = (unsigned short*)(ws + off); off += (16u << 20);
  unsigned short* aout  = (unsigned short*)(ws + off); off += (16u << 20);
  unsigned short* qb    = (unsigned short*)(ws + off); off += (16u << 20);
  unsigned short* kb    = (unsigned short*)(ws + off); off += (16u << 20);
  unsigned short* vb    = (unsigned short*)(ws + off);

  float* out  = (float*)d_out;
  float* embo = out + 8388608;     // [B,H,S,S]
  float* atto = out + 41943040;    // [B,H,S,S]

  bias_kernel<<<256, 256, 0, stream>>>(emb, clue, biasb);
  emb_bcast<<<4096, 256, 0, stream>>>(biasb, embo);
  wtrans<<<dim3(32, 32), 256, 0, stream>>>(Wq, WTq);
  wtrans<<<dim3(32, 32), 256, 0, stream>>>(Wk, WTk);
  wtrans<<<dim3(32, 32), 256, 0, stream>>>(Wv, WTv);
  wtrans<<<dim3(32, 32), 256, 0, stream>>>(Wo, WTo);

  cvt_bf16<<<1024, 256, 0, stream>>>(q, qb);
  cvt_bf16<<<1024, 256, 0, stream>>>(k, kb);
  cvt_bf16<<<1024, 256, 0, stream>>>(v, vb);

  gemm_kernel<0><<<dim3(8, 64), 256, 0, stream>>>(qb, WTq, bq, qh);
  gemm_kernel<0><<<dim3(8, 64), 256, 0, stream>>>(kb, WTk, bk, kh);
  gemm_kernel<1><<<dim3(8, 64), 256, 0, stream>>>(vb, WTv, bv, vhT);

  attn_kernel<<<dim3(2, 16, 32), 256, 0, stream>>>(qh, kh, vhT, biasb, mask, atto, aout);

  gemm_kernel<2><<<dim3(8, 64), 256, 0, stream>>>(aout, WTo, bo, out);
}

// Round 9
// 572.728 us; speedup vs baseline: 1.3210x; 1.0539x over previous
//
#include <hip/hip_runtime.h>
#include <stdint.h>

// ---------------------------------------------------------------------------
// Problem constants: B=32, S=256, HID=1024, HEADS=16, DK=64, CLUE(runtime)=64
// ---------------------------------------------------------------------------
typedef __bf16 bf16_t;
typedef bf16_t bf16x8 __attribute__((ext_vector_type(8)));
typedef float f32x4 __attribute__((ext_vector_type(4)));

__device__ __forceinline__ unsigned short f2bf(float f) {
  __bf16 h = (__bf16)f;            // RNE, compiles to v_cvt (m240: don't hand-write)
  unsigned short u;
  __builtin_memcpy(&u, &h, 2);
  return u;
}

__device__ __forceinline__ void gload16(const unsigned short* g, unsigned short* l) {
  auto gp = (const __attribute__((address_space(1))) unsigned short*)(g);
  auto lp = (__attribute__((address_space(3))) unsigned short*)(l);
  __builtin_amdgcn_global_load_lds(gp, lp, 16, 0, 0);   // 16B/lane, dest = base + lane*16
}

// d(i,j): |i-j| when i,j on the same side of clue, else 1  (fp matrix of ref)
__device__ __forceinline__ int relidx(int i, int j, int clue) {
  return ((i >= clue) == (j >= clue)) ? (i > j ? i - j : j - i) : 1;
}

// ---------------------------------------------------------------------------
// prep kernel — blockIdx partition:
//   [0,4096):      embedding output = emb[d(i,j)] broadcast to [B,H,S,S]
//   [4096,7168):   q/k/v f32 -> bf16 (1024 blocks each)
//   [7168,11264):  Wq/Wk/Wv/Wo [K][N] f32 -> WT [N][K] bf16 (1024 blocks each)
// ---------------------------------------------------------------------------
__global__ __launch_bounds__(256) void prep_kernel(
    const float* __restrict__ q, const float* __restrict__ k, const float* __restrict__ v,
    const float* __restrict__ Wq, const float* __restrict__ Wk,
    const float* __restrict__ Wv, const float* __restrict__ Wo,
    const float* __restrict__ emb, const int* __restrict__ cluep,
    float* __restrict__ embo, unsigned short* __restrict__ qkvb,
    unsigned short* __restrict__ WT) {
  __shared__ float tile[32][33];
  const int bid = blockIdx.x, tid = threadIdx.x;

  if (bid < 4096) {
    const int clue = cluep[0];
    float4* o4 = reinterpret_cast<float4*>(embo);
    #pragma unroll
    for (int it = 0; it < 8; ++it) {
      const int i4 = bid * 2048 + it * 256 + tid;
      const int fpos = (i4 & 16383) * 4;       // position within one [S,S] tile
      const int i = fpos >> 8, j0 = fpos & 255;
      float4 r;
      r.x = emb[relidx(i, j0 + 0, clue)];
      r.y = emb[relidx(i, j0 + 1, clue)];
      r.z = emb[relidx(i, j0 + 2, clue)];
      r.w = emb[relidx(i, j0 + 3, clue)];
      o4[i4] = r;
    }
  } else if (bid < 7168) {
    const int local = bid - 4096;
    const int which = local >> 10, lb = local & 1023;
    const float* in_ = which == 0 ? q : which == 1 ? k : v;
    unsigned short* out_ = qkvb + (size_t)which * 8388608;
    for (int i = lb * 256 + tid; i < 1048576; i += 262144) {   // 8 elems/iter
      float4 a = reinterpret_cast<const float4*>(in_)[2 * i];
      float4 b = reinterpret_cast<const float4*>(in_)[2 * i + 1];
      ushort4 p, qq;
      p.x = f2bf(a.x); p.y = f2bf(a.y); p.z = f2bf(a.z); p.w = f2bf(a.w);
      qq.x = f2bf(b.x); qq.y = f2bf(b.y); qq.z = f2bf(b.z); qq.w = f2bf(b.w);
      reinterpret_cast<ushort4*>(out_)[2 * i] = p;
      reinterpret_cast<ushort4*>(out_)[2 * i + 1] = qq;
    }
  } else {
    const int local = bid - 7168;
    const int which = local >> 10, wl = local & 1023;
    const float* in_ = which == 0 ? Wq : which == 1 ? Wk : which == 2 ? Wv : Wo;
    unsigned short* out_ = WT + (size_t)which * 2097152;
    const int tx = tid & 31, ty = tid >> 5;
    const int k0 = (wl & 31) * 32, n0 = (wl >> 5) * 32;
    #pragma unroll
    for (int p = 0; p < 4; ++p)
      tile[ty + p * 8][tx] = in_[(size_t)(k0 + ty + p * 8) * 1024 + n0 + tx];
    __syncthreads();
    #pragma unroll
    for (int p = 0; p < 4; ++p)
      out_[(size_t)(n0 + ty + p * 8) * 1024 + k0 + tx] = f2bf(tile[tx][ty + p * 8]);
  }
}

// ---------------------------------------------------------------------------
// GEMM: C[8192][1024] = A(bf16) @ BT^T + bvec.  128x128 tile, BK=64, 4 waves,
// mfma_f32_16x16x32_bf16, global_load_lds(16) staging with pre-swizzled global
// source (linear LDS dest, XOR on read side — rule #21 both-sides).
// grid.z selects q/k/v slice (contiguous A/BT/C bases). mode==2: O-projection
// (f32 C). z==2 with mode==0: vhT[b,h,d,s] transposed epilogue.
// ---------------------------------------------------------------------------
constexpr int GK = 1024, GN = 1024;

__global__ __launch_bounds__(256, 3) void gemm_fused(
    const unsigned short* __restrict__ Abase, const unsigned short* __restrict__ BTbase,
    const float* __restrict__ b0, const float* __restrict__ b1, const float* __restrict__ b2,
    void* __restrict__ Cbase, int mode) {
  __shared__ unsigned short Alds[128 * 64];   // 16 KB, linear
  __shared__ unsigned short Blds[128 * 64];
  const int t = threadIdx.x;
  const int lane = t & 63;
  const int w = t >> 6;
  const int wr = (w >> 1) * 64;
  const int wc = (w & 1) * 64;
  const int m0 = blockIdx.y * 128;
  const int n0 = blockIdx.x * 128;
  const int zz = blockIdx.z;
  const int lg = lane >> 4;
  const int lr = lane & 15;

  const unsigned short* A  = Abase + (size_t)zz * 8388608;
  const unsigned short* BT = BTbase + (size_t)zz * 2097152;
  const float* bvec = zz == 0 ? b0 : zz == 1 ? b1 : b2;

  const int srow = w * 32 + (lane >> 3);            // + i*8
  const int gch  = (lane & 7) ^ ((lane >> 3) & 7);  // swizzled source chunk

  f32x4 acc[4][4] = {};

  for (int k0 = 0; k0 < GK; k0 += 64) {
    #pragma unroll
    for (int i = 0; i < 4; ++i) {
      gload16(A  + (size_t)(m0 + srow + i * 8) * GK + k0 + gch * 8,
              &Alds[(w * 32 + i * 8) * 64]);
      gload16(BT + (size_t)(n0 + srow + i * 8) * GK + k0 + gch * 8,
              &Blds[(w * 32 + i * 8) * 64]);
    }
    __syncthreads();
    #pragma unroll
    for (int ks = 0; ks < 2; ++ks) {
      bf16x8 af[4], bfr[4];
      #pragma unroll
      for (int m = 0; m < 4; ++m) {
        const int r = wr + m * 16 + lr;
        const int cc = (ks * 4 + lg) ^ (lr & 7);
        af[m] = *reinterpret_cast<const bf16x8*>(&Alds[r * 64 + cc * 8]);
      }
      #pragma unroll
      for (int n = 0; n < 4; ++n) {
        const int r = wc + n * 16 + lr;
        const int cc = (ks * 4 + lg) ^ (lr & 7);
        bfr[n] = *reinterpret_cast<const bf16x8*>(&Blds[r * 64 + cc * 8]);
      }
      __builtin_amdgcn_s_setprio(1);
      #pragma unroll
      for (int m = 0; m < 4; ++m) {
        #pragma unroll
        for (int n = 0; n < 4; ++n)
          acc[m][n] = __builtin_amdgcn_mfma_f32_16x16x32_bf16(af[m], bfr[n], acc[m][n], 0, 0, 0);
      }
      __builtin_amdgcn_s_setprio(0);
    }
    __syncthreads();
  }

  const int omode = (mode == 2) ? 2 : (zz == 2 ? 1 : 0);
  #pragma unroll
  for (int m = 0; m < 4; ++m) {
    #pragma unroll
    for (int n = 0; n < 4; ++n) {
      const int col = n0 + wc + n * 16 + lr;
      const float bv = bvec[col];
      const int rbase = m0 + wr + m * 16 + lg * 4;
      if (omode == 0) {
        unsigned short* C = (unsigned short*)Cbase + (size_t)zz * 8388608;
        #pragma unroll
        for (int j = 0; j < 4; ++j)
          C[(size_t)(rbase + j) * GN + col] = f2bf(acc[m][n][j] + bv);
      } else if (omode == 1) {
        unsigned short* C = (unsigned short*)Cbase + (size_t)zz * 8388608;  // vhT
        const int b = rbase >> 8, s = rbase & 255;
        const int h = col >> 6, d = col & 63;
        ushort4 pk;
        pk.x = f2bf(acc[m][n][0] + bv);
        pk.y = f2bf(acc[m][n][1] + bv);
        pk.z = f2bf(acc[m][n][2] + bv);
        pk.w = f2bf(acc[m][n][3] + bv);
        *reinterpret_cast<ushort4*>(&C[(size_t)((b * 16 + h) * 64 + d) * 256 + s]) = pk;
      } else {
        float* C = (float*)Cbase;
        #pragma unroll
        for (int j = 0; j < 4; ++j)
          C[(size_t)(rbase + j) * GN + col] = acc[m][n][j] + bv;
      }
    }
  }
}

// ---------------------------------------------------------------------------
// Attention: one block per (b, h, half-of-128-rows). 4 waves x 32 q-rows,
// waves fully independent. Bias gathered directly from emb[d] (800B, L1).
// ---------------------------------------------------------------------------
__device__ __forceinline__ int pidx(int row, int c) {
  return (row * 256 + c) ^ ((row & 15) << 3);
}

__global__ __launch_bounds__(256, 2) void attn_kernel(
    const unsigned short* __restrict__ qh, const unsigned short* __restrict__ kh,
    const unsigned short* __restrict__ vhT, const float* __restrict__ emb,
    const int* __restrict__ cluep, const int* __restrict__ mask,
    float* __restrict__ att_out, unsigned short* __restrict__ attn_out) {
  __shared__ unsigned short P[128 * 256];   // 64 KB exactly
  const int t = threadIdx.x;
  const int lane = t & 63, w = t >> 6;
  const int half = blockIdx.x, h = blockIdx.y, b = blockIdx.z;
  const int rows0 = half * 128;
  const int wrow = w * 32;
  const int lg = lane >> 4, lr = lane & 15;
  const float scale = 0.125f;
  const int clue = cluep[0];

  bf16x8 qf[2][2];
  #pragma unroll
  for (int m = 0; m < 2; ++m)
    #pragma unroll
    for (int ks = 0; ks < 2; ++ks)
      qf[m][ks] = *reinterpret_cast<const bf16x8*>(
          qh + (size_t)(b * 256 + rows0 + wrow + m * 16 + lr) * 1024 + h * 64 + ks * 32 + lg * 8);

  int rowm[2][4];
  #pragma unroll
  for (int m = 0; m < 2; ++m)
    #pragma unroll
    for (int j = 0; j < 4; ++j)
      rowm[m][j] = mask[b * 256 + rows0 + wrow + m * 16 + lg * 4 + j];

  float psum[2][4] = {};

  for (int ct = 0; ct < 4; ++ct) {       // 64-column chunks
    f32x4 acc[2][4] = {};
    #pragma unroll
    for (int ks = 0; ks < 2; ++ks) {
      bf16x8 kf[4];
      #pragma unroll
      for (int n = 0; n < 4; ++n)
        kf[n] = *reinterpret_cast<const bf16x8*>(
            kh + (size_t)(b * 256 + ct * 64 + n * 16 + lr) * 1024 + h * 64 + ks * 32 + lg * 8);
      __builtin_amdgcn_s_setprio(1);
      #pragma unroll
      for (int m = 0; m < 2; ++m)
        #pragma unroll
        for (int n = 0; n < 4; ++n)
          acc[m][n] = __builtin_amdgcn_mfma_f32_16x16x32_bf16(qf[m][ks], kf[n], acc[m][n], 0, 0, 0);
      __builtin_amdgcn_s_setprio(0);
    }
    #pragma unroll
    for (int n = 0; n < 4; ++n) {
      const int c = ct * 64 + n * 16 + lr;
      const int colm = mask[b * 256 + c];
      const bool cside = c >= clue;
      #pragma unroll
      for (int m = 0; m < 2; ++m) {
        const int rloc = wrow + m * 16 + lg * 4;
        #pragma unroll
        for (int j = 0; j < 4; ++j) {
          const int i = rows0 + rloc + j;
          const int d = (((i >= clue)) == cside) ? (i > c ? i - c : c - i) : 1;
          float s = acc[m][n][j] * scale + emb[d];
          float p = (rowm[m][j] & colm) ? __expf(s) : 0.f;
          psum[m][j] += p;
          P[pidx(rloc + j, c)] = f2bf(p);
        }
      }
    }
  }

  // row-sum butterfly over the 16 column-lanes
  #pragma unroll
  for (int off = 1; off < 16; off <<= 1)
    #pragma unroll
    for (int m = 0; m < 2; ++m)
      #pragma unroll
      for (int j = 0; j < 4; ++j)
        psum[m][j] += __shfl_xor(psum[m][j], off);

  // Phase 2: att output (normalized; masked rows give inv=0)
  const size_t att_base = (size_t)(b * 16 + h) * 65536;
  #pragma unroll
  for (int it = 0; it < 16; ++it) {
    const int m2 = it >> 3;
    const int lg2 = (it >> 1) & 3;
    const int b0 = (2 * it) & 3;
    const float s0 = __shfl(psum[m2][b0], lg2 * 16);
    const float s1 = __shfl(psum[m2][b0 + 1], lg2 * 16);
    const int rloc = wrow + it * 2 + (lane >> 5);
    const int rabs = rows0 + rloc;
    const float sum = (lane >= 32) ? s1 : s0;
    const float inv = sum > 0.f ? 1.f / sum : 0.f;
    const int c8 = (lane & 31) * 8;
    bf16x8 pv = *reinterpret_cast<const bf16x8*>(&P[pidx(rloc, c8)]);
    float4 o1, o2;
    o1.x = (float)pv[0] * inv; o1.y = (float)pv[1] * inv;
    o1.z = (float)pv[2] * inv; o1.w = (float)pv[3] * inv;
    o2.x = (float)pv[4] * inv; o2.y = (float)pv[5] * inv;
    o2.z = (float)pv[6] * inv; o2.w = (float)pv[7] * inv;
    *reinterpret_cast<float4*>(&att_out[att_base + (size_t)rabs * 256 + c8]) = o1;
    *reinterpret_cast<float4*>(&att_out[att_base + (size_t)rabs * 256 + c8 + 4]) = o2;
  }

  // Phase 3: O = P @ V
  f32x4 oacc[2][4] = {};
  for (int ks = 0; ks < 8; ++ks) {
    bf16x8 pa[2], vf[4];
    #pragma unroll
    for (int m = 0; m < 2; ++m)
      pa[m] = *reinterpret_cast<const bf16x8*>(&P[pidx(wrow + m * 16 + lr, ks * 32 + lg * 8)]);
    #pragma unroll
    for (int dn = 0; dn < 4; ++dn)
      vf[dn] = *reinterpret_cast<const bf16x8*>(
          vhT + (size_t)((b * 16 + h) * 64 + dn * 16 + lr) * 256 + ks * 32 + lg * 8);
    __builtin_amdgcn_s_setprio(1);
    #pragma unroll
    for (int m = 0; m < 2; ++m)
      #pragma unroll
      for (int dn = 0; dn < 4; ++dn)
        oacc[m][dn] = __builtin_amdgcn_mfma_f32_16x16x32_bf16(pa[m], vf[dn], oacc[m][dn], 0, 0, 0);
    __builtin_amdgcn_s_setprio(0);
  }
  #pragma unroll
  for (int m = 0; m < 2; ++m) {
    #pragma unroll
    for (int dn = 0; dn < 4; ++dn) {
      #pragma unroll
      for (int j = 0; j < 4; ++j) {
        const int rloc = wrow + m * 16 + lg * 4 + j;
        const float sum = psum[m][j];
        const float inv = sum > 0.f ? 1.f / sum : 0.f;
        attn_out[(size_t)(b * 256 + rows0 + rloc) * 1024 + h * 64 + dn * 16 + lr] =
            f2bf(oacc[m][dn][j] * inv);
      }
    }
  }
}

// ---------------------------------------------------------------------------
extern "C" void kernel_launch(void* const* d_in, const int* in_sizes, int n_in,
                              void* d_out, int out_size, void* d_ws, size_t ws_size,
                              hipStream_t stream) {
  (void)in_sizes; (void)n_in; (void)out_size; (void)ws_size;
  const float* q    = (const float*)d_in[0];
  const float* k    = (const float*)d_in[1];
  const float* v    = (const float*)d_in[2];
  const int*   clue = (const int*)d_in[3];
  const int*   mask = (const int*)d_in[4];
  const float* Wq   = (const float*)d_in[5];
  const float* bq   = (const float*)d_in[6];
  const float* Wk   = (const float*)d_in[7];
  const float* bk   = (const float*)d_in[8];
  const float* Wv   = (const float*)d_in[9];
  const float* bv   = (const float*)d_in[10];
  const float* Wo   = (const float*)d_in[11];
  const float* bo   = (const float*)d_in[12];
  const float* emb  = (const float*)d_in[13];

  char* ws = (char*)d_ws;
  unsigned short* WT   = (unsigned short*)(ws);                 // 4 x 2M ushorts = 16MB
  size_t off = 16u << 20;
  unsigned short* qh   = (unsigned short*)(ws + off); off += (16u << 20);
  unsigned short* kh   = (unsigned short*)(ws + off); off += (16u << 20);
  unsigned short* vhT  = (unsigned short*)(ws + off); off += (16u << 20);
  unsigned short* aout = (unsigned short*)(ws + off); off += (16u << 20);
  unsigned short* qkvb = (unsigned short*)(ws + off);           // qb,kb,vb contiguous 48MB
  (void)kh; (void)vhT;

  float* out  = (float*)d_out;
  float* embo = out + 8388608;     // [B,H,S,S]
  float* atto = out + 41943040;    // [B,H,S,S]

  prep_kernel<<<11264, 256, 0, stream>>>(q, k, v, Wq, Wk, Wv, Wo, emb, clue,
                                         embo, qkvb, WT);
  gemm_fused<<<dim3(8, 64, 3), 256, 0, stream>>>(qkvb, WT, bq, bk, bv, qh, 0);
  attn_kernel<<<dim3(2, 16, 32), 256, 0, stream>>>(qh, kh, vhT, emb, clue, mask, atto, aout);
  gemm_fused<<<dim3(8, 64, 1), 256, 0, stream>>>(aout, WT + 3 * 2097152, bo, bo, bo, out, 2);
}